// Round 3
// baseline (635.618 us; speedup 1.0000x reference)
//
#include <hip/hip_runtime.h>

// B=32 H=8 NQ=64 NK=4096 DIN=512 DV=64 DM=512
typedef short bf16x8 __attribute__((ext_vector_type(8)));
typedef short bf16x4 __attribute__((ext_vector_type(4)));
typedef float f32x4 __attribute__((ext_vector_type(4)));

__device__ __forceinline__ unsigned short f2bf(float f) {
  union { float f; unsigned u; } v; v.f = f;
  unsigned r = v.u + 0x7fffu + ((v.u >> 16) & 1u);   // RNE
  return (unsigned short)(r >> 16);
}

__device__ __forceinline__ void gld_lds16(const void* g, void* l) {
  __builtin_amdgcn_global_load_lds(
      (const __attribute__((address_space(1))) void*)g,
      (__attribute__((address_space(3))) void*)l, 16, 0, 0);
}

// ---------------------------------------------------------------------------
// Wv fp32 -> bf16 (262144 elems, grid 256)
__global__ __launch_bounds__(256) void convWv(const float* __restrict__ in,
                                              unsigned short* __restrict__ out) {
  long i = (long)(blockIdx.x * 256 + threadIdx.x) * 4;
  f32x4 d = *(const f32x4*)(in + i);
  bf16x4 o;
  o[0] = (short)f2bf(d[0]); o[1] = (short)f2bf(d[1]);
  o[2] = (short)f2bf(d[2]); o[3] = (short)f2bf(d[3]);
  *(bf16x4*)(out + i) = o;
}

// Wo fp32 [512 e][512 d] -> Wo2 bf16 [512 e][1024] duplicated along k'
__global__ __launch_bounds__(256) void convWo2(const float* __restrict__ in,
                                               unsigned short* __restrict__ out) {
  long i4 = (long)(blockIdx.x * 256 + threadIdx.x) * 4;
  int e = (int)(i4 >> 9), c = (int)(i4 & 511);
  f32x4 d = *(const f32x4*)(in + i4);
  bf16x4 o;
  o[0] = (short)f2bf(d[0]); o[1] = (short)f2bf(d[1]);
  o[2] = (short)f2bf(d[2]); o[3] = (short)f2bf(d[3]);
  *(bf16x4*)(out + (long)e * 1024 + c) = o;
  *(bf16x4*)(out + (long)e * 1024 + 512 + c) = o;
}

// ---------------------------------------------------------------------------
// vT[b][d=(h,dv)][nk] = sum_c Wv[d][c] * V[b][nk][c]   (bf16 out, no bias)
// A = Wvb bf16 (async), B = V fp32 (VGPR load + cvt + LDS). 128x128 tiles, BK=64.
__global__ __launch_bounds__(256, 2) void vt_gemm(
    const unsigned short* __restrict__ Wvb, const float* __restrict__ V,
    unsigned short* __restrict__ vT) {
  const int t = threadIdx.x, lane = t & 63, wave = t >> 6;
  const int n0 = blockIdx.x * 128;   // nk
  const int m0 = blockIdx.y * 128;   // d
  const int b = blockIdx.z;
  const float* Vb = V + (long)b * (4096L * 512) + (long)n0 * 512;

  __shared__ __align__(16) unsigned short As[128 * 64];
  __shared__ __align__(16) unsigned short Bs[128 * 64];

  const int wm = (wave >> 1) * 64, wn = (wave & 1) * 64;
  const int l16 = lane & 15, quad = lane >> 4;
  const int bchunk = (t & 15) * 4, brow0 = t >> 4;

  f32x4 acc[4][4];
#pragma unroll
  for (int i = 0; i < 4; ++i)
#pragma unroll
    for (int j = 0; j < 4; ++j) acc[i][j] = (f32x4){0.f, 0.f, 0.f, 0.f};

  for (int k0 = 0; k0 < 512; k0 += 64) {
    // A async: 128x64 bf16 = 16 KB = 4 shots
#pragma unroll
    for (int s = 0; s < 4; ++s) {
      int li = s * 256 + t;
      int row = li >> 3, kq = (li & 7) * 8;
      gld_lds16(Wvb + (long)(m0 + row) * 512 + k0 + kq, (char*)As + (s * 256 + wave * 64) * 16);
    }
    // B: fp32 coalesced loads, cvt to bf16, conflict-light b64 LDS writes
#pragma unroll
    for (int j = 0; j < 8; ++j) {
      int row = brow0 + 16 * j;
      f32x4 d = *(const f32x4*)(Vb + (long)row * 512 + k0 + bchunk);
      bf16x4 p;
      p[0] = (short)f2bf(d[0]); p[1] = (short)f2bf(d[1]);
      p[2] = (short)f2bf(d[2]); p[3] = (short)f2bf(d[3]);
      *(bf16x4*)(Bs + row * 64 + bchunk) = p;
    }
    __syncthreads();
#pragma unroll
    for (int ks = 0; ks < 2; ++ks) {
      bf16x8 af[4], bfv[4];
#pragma unroll
      for (int i = 0; i < 4; ++i)
        af[i] = *(const bf16x8*)(As + (wm + i * 16 + l16) * 64 + ks * 32 + quad * 8);
#pragma unroll
      for (int j = 0; j < 4; ++j)
        bfv[j] = *(const bf16x8*)(Bs + (wn + j * 16 + l16) * 64 + ks * 32 + quad * 8);
#pragma unroll
      for (int i = 0; i < 4; ++i)
#pragma unroll
        for (int j = 0; j < 4; ++j)
          acc[i][j] = __builtin_amdgcn_mfma_f32_16x16x32_bf16(af[i], bfv[j], acc[i][j], 0, 0, 0);
    }
    __syncthreads();
  }
  unsigned short* o = vT + (long)b * 2097152;
#pragma unroll
  for (int i = 0; i < 4; ++i)
#pragma unroll
    for (int j = 0; j < 4; ++j) {
      int col = n0 + wn + j * 16 + l16;
#pragma unroll
      for (int r = 0; r < 4; ++r) {
        int row = m0 + wm + i * 16 + quad * 4 + r;
        o[(long)row * 4096 + col] = f2bf(acc[i][j][r]);
      }
    }
}

// ---------------------------------------------------------------------------
// Fused attention GEMM per (b,h,part): O32[part][(b,q)][(h,dv)] = sum_k exp(l)*vT
// (unnormalized); also Zp[part][b,h,q] = row sums. 4 waves split the 2048-k range.
__global__ __launch_bounds__(256, 2) void o_gemm(
    const float* __restrict__ att12, const float* __restrict__ att3,
    const unsigned short* __restrict__ vT, float* __restrict__ O32,
    float* __restrict__ Zp) {
  const int bh = blockIdx.x, part = blockIdx.y;
  const int b = bh >> 3, h = bh & 7;
  const int t = threadIdx.x, lane = t & 63, wave = t >> 6;

  __shared__ __align__(16) unsigned short As[4 * 64 * 32];
  __shared__ __align__(16) unsigned short Bs[4 * 64 * 32];
  __shared__ float Ored[64 * 64];
  __shared__ float Zl[4][64];

  const unsigned short* vTb = vT + (long)b * 2097152 + (long)h * 64 * 4096;
  const int gq = t & 63, gw = t >> 6;               // A-gen: (window=wave, q)
  const float* a3row = att3 + ((long)bh * 64 + gq) * 256;
  const float* a12b = att12 + (long)b * 32768 + h * 16;
  const int l16 = lane & 15, quad = lane >> 4;
  const int kw0 = part * 2048 + gw * 512;

  f32x4 acc[4][4];
#pragma unroll
  for (int i = 0; i < 4; ++i)
#pragma unroll
    for (int j = 0; j < 4; ++j) acc[i][j] = (f32x4){0.f, 0.f, 0.f, 0.f};
  float zacc = 0.f;

  for (int it = 0; it < 16; ++it) {
    // B: 4 windows x 64 dv x 32 k bf16 = 16 KB async (shot s = window s)
#pragma unroll
    for (int s = 0; s < 4; ++s) {
      int row = t >> 2, kq = (t & 3) * 8;
      int kk = part * 2048 + s * 512 + it * 32 + kq;
      gld_lds16(vTb + (long)row * 4096 + kk, (char*)Bs + s * 4096 + wave * 1024);
    }
    // A-gen: P[q][k] = exp(att12*att3) for this wave's k-window
    {
      int kbase = kw0 + it * 32;
      int ch = kbase >> 8, fh = (kbase >> 6) & 3, cw0 = (kbase >> 2) & 15;
      f32x4 y0 = *(const f32x4*)(a3row + ch * 16 + cw0);
      f32x4 y1 = *(const f32x4*)(a3row + ch * 16 + cw0 + 4);
      const float* ap = a12b + ch * 2048 + cw0 * 128 + fh * 4;
      bf16x8 p[4];
#pragma unroll
      for (int cw = 0; cw < 8; ++cw) {
        float y = (cw < 4) ? y0[cw] : y1[cw - 4];
        f32x4 x = *(const f32x4*)(ap + cw * 128);
#pragma unroll
        for (int fw = 0; fw < 4; ++fw) {
          float e = __expf(x[fw] * y);
          zacc += e;
          p[cw >> 1][(cw & 1) * 4 + fw] = (short)f2bf(e);
        }
      }
#pragma unroll
      for (int g = 0; g < 4; ++g)
        *(bf16x8*)(As + gw * 2048 + gq * 32 + g * 8) = p[g];
    }
    __syncthreads();
    bf16x8 af[4], bfv[4];
#pragma unroll
    for (int i = 0; i < 4; ++i)
      af[i] = *(const bf16x8*)(As + wave * 2048 + (i * 16 + l16) * 32 + quad * 8);
#pragma unroll
    for (int j = 0; j < 4; ++j)
      bfv[j] = *(const bf16x8*)(Bs + wave * 2048 + (j * 16 + l16) * 32 + quad * 8);
#pragma unroll
    for (int i = 0; i < 4; ++i)
#pragma unroll
      for (int j = 0; j < 4; ++j)
        acc[i][j] = __builtin_amdgcn_mfma_f32_16x16x32_bf16(af[i], bfv[j], acc[i][j], 0, 0, 0);
    __syncthreads();
  }

  Zl[gw][gq] = zacc;
  // sum the 4 wave-accumulators (disjoint k-slices) into Ored
#pragma unroll
  for (int w = 0; w < 4; ++w) {
    if (wave == w) {
#pragma unroll
      for (int i = 0; i < 4; ++i)
#pragma unroll
        for (int j = 0; j < 4; ++j) {
          int col = j * 16 + l16;
#pragma unroll
          for (int r = 0; r < 4; ++r) {
            int row = i * 16 + quad * 4 + r;
            if (w == 0) Ored[row * 64 + col] = acc[i][j][r];
            else Ored[row * 64 + col] += acc[i][j][r];
          }
        }
    }
    __syncthreads();
  }
  if (t < 64) {
    float z = Zl[0][t] + Zl[1][t] + Zl[2][t] + Zl[3][t];
    Zp[(long)part * 16384 + (long)bh * 64 + t] = z;
  }
  // store unnormalized partial: O32[part][(b*64+q)][h*64+dv]
  {
    int q = t >> 2, c0 = (t & 3) * 16;
    float* op = O32 + (long)part * 1048576 + ((long)(b * 64 + q)) * 512 + h * 64 + c0;
#pragma unroll
    for (int j = 0; j < 4; ++j)
      *(f32x4*)(op + j * 4) = *(const f32x4*)(Ored + q * 64 + c0 + j * 4);
  }
}

// ---------------------------------------------------------------------------
__global__ __launch_bounds__(256) void rzcomb(const float* __restrict__ Zp,
                                              float* __restrict__ rZ) {
  int i = blockIdx.x * 256 + threadIdx.x;
  rZ[i] = 1.0f / (Zp[i] + Zp[16384 + i]);
}

// ---------------------------------------------------------------------------
// out[(b,q)][e] = sum_{k'<1024} (rZ*O32[part] + (part==0)*b_v)[m][k'] * Wo2[e][k'] + b_o
// A staged fp32->bf16 with fused normalize+bias; B = Wo2 bf16 async. 64x128 tiles.
__global__ __launch_bounds__(256, 2) void wo_gemm(
    const float* __restrict__ O32, const float* __restrict__ rZ,
    const float* __restrict__ b_v, const unsigned short* __restrict__ Wo2,
    const float* __restrict__ b_o, float* __restrict__ out) {
  const int t = threadIdx.x, lane = t & 63, wave = t >> 6;
  const int n0 = blockIdx.x * 128;   // e
  const int m0 = blockIdx.y * 64;    // (b,q)

  __shared__ __align__(16) unsigned short As[64 * 32];
  __shared__ __align__(16) unsigned short Bs[128 * 32];

  const int wm = (wave >> 1) * 32, wn = (wave & 1) * 64;
  const int l16 = lane & 15, quad = lane >> 4;
  const int arow = t >> 2, akq = (t & 3) * 8;
  const int m = m0 + arow, ab = m >> 6, aq = m & 63;

  f32x4 acc[2][4];
#pragma unroll
  for (int i = 0; i < 2; ++i)
#pragma unroll
    for (int j = 0; j < 4; ++j) acc[i][j] = (f32x4){0.f, 0.f, 0.f, 0.f};

  for (int k0 = 0; k0 < 1024; k0 += 32) {
    int part = k0 >> 9, rem = k0 & 511;
    int hh = (rem + akq) >> 6;
    const float* src = O32 + (long)part * 1048576 + (long)m * 512 + rem + akq;
    f32x4 x0 = *(const f32x4*)(src);
    f32x4 x1 = *(const f32x4*)(src + 4);
    float rz = rZ[ab * 512 + hh * 64 + aq];
    f32x4 bv0 = (f32x4){0.f, 0.f, 0.f, 0.f}, bv1 = bv0;
    if (part == 0) {
      bv0 = *(const f32x4*)(b_v + rem + akq);
      bv1 = *(const f32x4*)(b_v + rem + akq + 4);
    }
    bf16x8 pa;
#pragma unroll
    for (int j = 0; j < 4; ++j) pa[j] = (short)f2bf(x0[j] * rz + bv0[j]);
#pragma unroll
    for (int j = 0; j < 4; ++j) pa[4 + j] = (short)f2bf(x1[j] * rz + bv1[j]);
    *(bf16x8*)(As + arow * 32 + akq) = pa;
    // B async: 128x32 bf16 = 8 KB = 2 shots
#pragma unroll
    for (int s = 0; s < 2; ++s) {
      int li = s * 256 + t;
      int row = li >> 2, kq = (li & 3) * 8;
      gld_lds16(Wo2 + (long)(n0 + row) * 1024 + k0 + kq, (char*)Bs + (s * 256 + wave * 64) * 16);
    }
    __syncthreads();
    bf16x8 af[2], bfv[4];
#pragma unroll
    for (int i = 0; i < 2; ++i)
      af[i] = *(const bf16x8*)(As + (wm + i * 16 + l16) * 32 + quad * 8);
#pragma unroll
    for (int j = 0; j < 4; ++j)
      bfv[j] = *(const bf16x8*)(Bs + (wn + j * 16 + l16) * 32 + quad * 8);
#pragma unroll
    for (int i = 0; i < 2; ++i)
#pragma unroll
      for (int j = 0; j < 4; ++j)
        acc[i][j] = __builtin_amdgcn_mfma_f32_16x16x32_bf16(af[i], bfv[j], acc[i][j], 0, 0, 0);
    __syncthreads();
  }
#pragma unroll
  for (int i = 0; i < 2; ++i)
#pragma unroll
    for (int j = 0; j < 4; ++j) {
      int col = n0 + wn + j * 16 + l16;
#pragma unroll
      for (int r = 0; r < 4; ++r) {
        int row = wm + i * 16 + quad * 4 + r;
        out[(long)(m0 + row) * 512 + col] = acc[i][j][r] + b_o[col];
      }
    }
}

// ---------------------------------------------------------------------------
extern "C" void kernel_launch(void* const* d_in, const int* in_sizes, int n_in,
                              void* d_out, int out_size, void* d_ws, size_t ws_size,
                              hipStream_t stream) {
  const float* att12 = (const float*)d_in[0];
  const float* att3  = (const float*)d_in[1];
  const float* values = (const float*)d_in[2];
  const float* W_v = (const float*)d_in[3];
  const float* b_v = (const float*)d_in[4];
  const float* W_o = (const float*)d_in[5];
  const float* b_o = (const float*)d_in[6];
  float* out = (float*)d_out;

  char* ws = (char*)d_ws;
  unsigned short* vT  = (unsigned short*)(ws);                 // 128 MB [32][512][4096]
  float*          O32 = (float*)(ws + 134217728L);             // 8 MB [2][2048][512]
  float*          Zp  = (float*)(ws + 142606336L);             // 128 KB [2][16384]
  float*          rZ  = (float*)(ws + 142737408L);             // 64 KB
  unsigned short* Wvb = (unsigned short*)(ws + 142802944L);    // 512 KB
  unsigned short* Wo2 = (unsigned short*)(ws + 143327232L);    // 1 MB

  convWv<<<dim3(256), dim3(256), 0, stream>>>(W_v, Wvb);
  convWo2<<<dim3(256), dim3(256), 0, stream>>>(W_o, Wo2);

  vt_gemm<<<dim3(32, 4, 32), dim3(256), 0, stream>>>(Wvb, values, vT);

  o_gemm<<<dim3(256, 2), dim3(256), 0, stream>>>(att12, att3, vT, O32, Zp);

  rzcomb<<<dim3(64), dim3(256), 0, stream>>>(Zp, rZ);

  wo_gemm<<<dim3(4, 32), dim3(256), 0, stream>>>(O32, rZ, b_v, Wo2, b_o, out);

  (void)in_sizes; (void)n_in; (void)out_size; (void)ws_size;
}

// Round 4
// 556.313 us; speedup vs baseline: 1.1426x; 1.1426x over previous
//
#include <hip/hip_runtime.h>

// B=32 H=8 NQ=64 NK=4096 DIN=512 DV=64 DM=512
typedef short bf16x8 __attribute__((ext_vector_type(8)));
typedef short bf16x4 __attribute__((ext_vector_type(4)));
typedef float f32x4 __attribute__((ext_vector_type(4)));

__device__ __forceinline__ unsigned short f2bf(float f) {
  union { float f; unsigned u; } v; v.f = f;
  unsigned r = v.u + 0x7fffu + ((v.u >> 16) & 1u);   // RNE
  return (unsigned short)(r >> 16);
}

__device__ __forceinline__ void gld_lds16(const void* g, void* l) {
  __builtin_amdgcn_global_load_lds(
      (const __attribute__((address_space(1))) void*)g,
      (__attribute__((address_space(3))) void*)l, 16, 0, 0);
}

// ---------------------------------------------------------------------------
// fp32 -> bf16 (262144 elems, grid 256) — used for W_v and W_o
__global__ __launch_bounds__(256) void convW(const float* __restrict__ in,
                                             unsigned short* __restrict__ out) {
  long i = (long)(blockIdx.x * 256 + threadIdx.x) * 4;
  f32x4 d = *(const f32x4*)(in + i);
  bf16x4 o;
  o[0] = (short)f2bf(d[0]); o[1] = (short)f2bf(d[1]);
  o[2] = (short)f2bf(d[2]); o[3] = (short)f2bf(d[3]);
  *(bf16x4*)(out + i) = o;
}

// bias2[e] = b_o[e] + sum_d b_v[d] * W_o[e][d]   (exact: softmax rows sum to 1)
__global__ __launch_bounds__(256) void bias2_kernel(const float* __restrict__ Wo,
                                                    const float* __restrict__ b_v,
                                                    const float* __restrict__ b_o,
                                                    float* __restrict__ bias2) {
  int e = blockIdx.x * 256 + threadIdx.x;
  const float* wrow = Wo + (long)e * 512;
  float s = 0.f;
#pragma unroll 4
  for (int d = 0; d < 512; d += 4) {
    f32x4 w = *(const f32x4*)(wrow + d);
    f32x4 bv = *(const f32x4*)(b_v + d);
    s += w[0] * bv[0] + w[1] * bv[1] + w[2] * bv[2] + w[3] * bv[3];
  }
  bias2[e] = s + b_o[e];
}

// ---------------------------------------------------------------------------
// vT[b][d][nk] = sum_c Wv[d][c] * V[b][nk][c]   (bf16 out)
// BK=32 (m97 geometry: 64-byte row stride, conflict-free). A async, B via VGPR+cvt.
__global__ __launch_bounds__(256, 2) void vt_gemm(
    const unsigned short* __restrict__ Wvb, const float* __restrict__ V,
    unsigned short* __restrict__ vT) {
  const int t = threadIdx.x, lane = t & 63, wave = t >> 6;
  const int n0 = blockIdx.x * 128;   // nk
  const int m0 = blockIdx.y * 128;   // d
  const int b = blockIdx.z;
  const float* Vb = V + (long)b * (4096L * 512) + (long)n0 * 512;

  __shared__ __align__(16) unsigned short As[128 * 32];
  __shared__ __align__(16) unsigned short Bs[128 * 32];

  const int wm = (wave >> 1) * 64, wn = (wave & 1) * 64;
  const int l16 = lane & 15, quad = lane >> 4;
  const int brow0 = t >> 3, bc4 = (t & 7) * 4;   // B-load: 8 lanes/row, coalesced

  f32x4 acc[4][4];
#pragma unroll
  for (int i = 0; i < 4; ++i)
#pragma unroll
    for (int j = 0; j < 4; ++j) acc[i][j] = (f32x4){0.f, 0.f, 0.f, 0.f};

  for (int k0 = 0; k0 < 512; k0 += 32) {
    // A async: 128x32 bf16 = 8 KB = 2 shots
#pragma unroll
    for (int s = 0; s < 2; ++s) {
      int li = s * 256 + t;
      int row = li >> 2, kq = (li & 3) * 8;
      gld_lds16(Wvb + (long)(m0 + row) * 512 + k0 + kq, (char*)As + (s * 256 + wave * 64) * 16);
    }
    // B: 128 rows x 32 c fp32, coalesced f32x4, cvt, b64 LDS writes (2-way max)
#pragma unroll
    for (int j = 0; j < 4; ++j) {
      int row = brow0 + 32 * j;
      f32x4 d = *(const f32x4*)(Vb + (long)row * 512 + k0 + bc4);
      bf16x4 p;
      p[0] = (short)f2bf(d[0]); p[1] = (short)f2bf(d[1]);
      p[2] = (short)f2bf(d[2]); p[3] = (short)f2bf(d[3]);
      *(bf16x4*)(Bs + row * 32 + bc4) = p;
    }
    __syncthreads();
    bf16x8 af[4], bfv[4];
#pragma unroll
    for (int i = 0; i < 4; ++i)
      af[i] = *(const bf16x8*)(As + (wm + i * 16 + l16) * 32 + quad * 8);
#pragma unroll
    for (int j = 0; j < 4; ++j)
      bfv[j] = *(const bf16x8*)(Bs + (wn + j * 16 + l16) * 32 + quad * 8);
#pragma unroll
    for (int i = 0; i < 4; ++i)
#pragma unroll
      for (int j = 0; j < 4; ++j)
        acc[i][j] = __builtin_amdgcn_mfma_f32_16x16x32_bf16(af[i], bfv[j], acc[i][j], 0, 0, 0);
    __syncthreads();
  }
  unsigned short* o = vT + (long)b * 2097152;
#pragma unroll
  for (int i = 0; i < 4; ++i)
#pragma unroll
    for (int j = 0; j < 4; ++j) {
      int col = n0 + wn + j * 16 + l16;
#pragma unroll
      for (int r = 0; r < 4; ++r) {
        int row = m0 + wm + i * 16 + quad * 4 + r;
        o[(long)row * 4096 + col] = f2bf(acc[i][j][r]);
      }
    }
}

// ---------------------------------------------------------------------------
// Fused attention per (b,h): U[b][q][h*64+dv] = (1/Z_q) sum_k exp(a12*a3) * vT[d][k]
// Full K=4096 in one block: 4 waves x 1024-k windows; in-block Z; bf16 out.
__global__ __launch_bounds__(256, 2) void o_gemm(
    const float* __restrict__ att12, const float* __restrict__ att3,
    const unsigned short* __restrict__ vT, unsigned short* __restrict__ U) {
  const int bh = blockIdx.x;
  const int b = bh >> 3, h = bh & 7;
  const int t = threadIdx.x, lane = t & 63, wave = t >> 6;

  __shared__ __align__(16) unsigned short As[4 * 64 * 32];
  __shared__ __align__(16) unsigned short Bs[4 * 64 * 32];
  __shared__ float Ored[64 * 68];   // stride 68: 16B-aligned rows, 2-way banks max
  __shared__ float Zl[4][64];
  __shared__ float rZa[64];

  const unsigned short* vTb = vT + (long)b * 2097152 + (long)h * 64 * 4096;
  const int gq = t & 63, gw = t >> 6;          // A-gen: (k-window = wave, q)
  const float* a3row = att3 + ((long)bh * 64 + gq) * 256;
  const float* a12b = att12 + (long)b * 32768 + h * 16;
  const int l16 = lane & 15, quad = lane >> 4;

  f32x4 acc[4][4];
#pragma unroll
  for (int i = 0; i < 4; ++i)
#pragma unroll
    for (int j = 0; j < 4; ++j) acc[i][j] = (f32x4){0.f, 0.f, 0.f, 0.f};
  float zacc = 0.f;

  for (int it = 0; it < 32; ++it) {
    // B: 4 windows x 64 dv x 32 k bf16 = 16 KB async (shot s = window s)
#pragma unroll
    for (int s = 0; s < 4; ++s) {
      int row = t >> 2, kq = (t & 3) * 8;
      int kk = s * 1024 + it * 32 + kq;
      gld_lds16(vTb + (long)row * 4096 + kk, (char*)Bs + s * 4096 + wave * 1024);
    }
    // A-gen: P[q][k] = exp(att12*att3) for this wave's k-window (each exp once)
    {
      int kbase = gw * 1024 + it * 32;
      int ch = kbase >> 8, fh = (kbase >> 6) & 3, cw0 = (kbase >> 2) & 15;
      f32x4 y0 = *(const f32x4*)(a3row + ch * 16 + cw0);
      f32x4 y1 = *(const f32x4*)(a3row + ch * 16 + cw0 + 4);
      const float* ap = a12b + ch * 2048 + cw0 * 128 + fh * 4;
      bf16x8 p[4];
#pragma unroll
      for (int cw = 0; cw < 8; ++cw) {
        float y = (cw < 4) ? y0[cw] : y1[cw - 4];
        f32x4 x = *(const f32x4*)(ap + cw * 128);
#pragma unroll
        for (int fw = 0; fw < 4; ++fw) {
          float e = __expf(x[fw] * y);
          zacc += e;
          p[cw >> 1][(cw & 1) * 4 + fw] = (short)f2bf(e);
        }
      }
#pragma unroll
      for (int g = 0; g < 4; ++g)
        *(bf16x8*)(As + gw * 2048 + gq * 32 + g * 8) = p[g];
    }
    __syncthreads();
    bf16x8 af[4], bfv[4];
#pragma unroll
    for (int i = 0; i < 4; ++i)
      af[i] = *(const bf16x8*)(As + wave * 2048 + (i * 16 + l16) * 32 + quad * 8);
#pragma unroll
    for (int j = 0; j < 4; ++j)
      bfv[j] = *(const bf16x8*)(Bs + wave * 2048 + (j * 16 + l16) * 32 + quad * 8);
#pragma unroll
    for (int i = 0; i < 4; ++i)
#pragma unroll
      for (int j = 0; j < 4; ++j)
        acc[i][j] = __builtin_amdgcn_mfma_f32_16x16x32_bf16(af[i], bfv[j], acc[i][j], 0, 0, 0);
    __syncthreads();
  }

  Zl[gw][gq] = zacc;
  __syncthreads();
  if (t < 64) rZa[t] = 1.0f / (Zl[0][t] + Zl[1][t] + Zl[2][t] + Zl[3][t]);
  // sum the 4 wave-accumulators (disjoint k-slices) into Ored
#pragma unroll
  for (int w = 0; w < 4; ++w) {
    if (wave == w) {
#pragma unroll
      for (int i = 0; i < 4; ++i)
#pragma unroll
        for (int j = 0; j < 4; ++j) {
          int col = j * 16 + l16;
#pragma unroll
          for (int r = 0; r < 4; ++r) {
            int row = i * 16 + quad * 4 + r;
            if (w == 0) Ored[row * 68 + col] = acc[i][j][r];
            else Ored[row * 68 + col] += acc[i][j][r];
          }
        }
    }
    __syncthreads();
  }
  // normalize + store bf16: U[(b*64+q)*512 + h*64 + dv]
  {
    int q = t >> 2, dv0 = (t & 3) * 16;
    float rz = rZa[q];
    unsigned short* up = U + ((long)(b * 64 + q)) * 512 + h * 64 + dv0;
    bf16x8 o0, o1;
#pragma unroll
    for (int j = 0; j < 8; ++j) o0[j] = (short)f2bf(Ored[q * 68 + dv0 + j] * rz);
#pragma unroll
    for (int j = 0; j < 8; ++j) o1[j] = (short)f2bf(Ored[q * 68 + dv0 + 8 + j] * rz);
    *(bf16x8*)(up) = o0;
    *(bf16x8*)(up + 8) = o1;
  }
}

// ---------------------------------------------------------------------------
// Generic bf16 GEMM (m97 structure) — final projection
template <int BM, int BN, bool OUT_BF16, bool ADD_BIAS>
__global__ __launch_bounds__(256, 2) void gemm_bt(
    const unsigned short* __restrict__ A, const unsigned short* __restrict__ Bt,
    void* __restrict__ C, const float* __restrict__ bias,
    int K, int lda, int ldb, int ldc) {
  constexpr int BK = 32;
  const int t = threadIdx.x;
  const int lane = t & 63;
  const int wave = t >> 6;
  const int m0 = blockIdx.y * BM;
  const int n0 = blockIdx.x * BN;

  A += (long)m0 * lda;
  Bt += (long)n0 * ldb;

  __shared__ __align__(16) unsigned short As[BM * BK];
  __shared__ __align__(16) unsigned short Bs[BN * BK];

  constexpr int TM = BM / 32;
  constexpr int TN = BN / 32;
  const int wm = (wave >> 1) * (BM / 2);
  const int wn = (wave & 1) * (BN / 2);
  const int l16 = lane & 15;
  const int quad = lane >> 4;

  f32x4 acc[TM][TN];
#pragma unroll
  for (int i = 0; i < TM; ++i)
#pragma unroll
    for (int j = 0; j < TN; ++j) acc[i][j] = (f32x4){0.f, 0.f, 0.f, 0.f};

  constexpr int ASHOT = (BM * 4) / 256;
  constexpr int BSHOT = (BN * 4) / 256;

  for (int k0 = 0; k0 < K; k0 += BK) {
#pragma unroll
    for (int s = 0; s < ASHOT; ++s) {
      int li = s * 256 + t;
      int row = li >> 2, kq = (li & 3) * 8;
      gld_lds16(A + (long)row * lda + k0 + kq, (char*)As + (s * 256 + wave * 64) * 16);
    }
#pragma unroll
    for (int s = 0; s < BSHOT; ++s) {
      int li = s * 256 + t;
      int row = li >> 2, kq = (li & 3) * 8;
      gld_lds16(Bt + (long)row * ldb + k0 + kq, (char*)Bs + (s * 256 + wave * 64) * 16);
    }
    __syncthreads();
    bf16x8 af[TM], bfv[TN];
#pragma unroll
    for (int i = 0; i < TM; ++i)
      af[i] = *(const bf16x8*)(As + (wm + i * 16 + l16) * BK + quad * 8);
#pragma unroll
    for (int j = 0; j < TN; ++j)
      bfv[j] = *(const bf16x8*)(Bs + (wn + j * 16 + l16) * BK + quad * 8);
#pragma unroll
    for (int i = 0; i < TM; ++i)
#pragma unroll
      for (int j = 0; j < TN; ++j)
        acc[i][j] = __builtin_amdgcn_mfma_f32_16x16x32_bf16(af[i], bfv[j], acc[i][j], 0, 0, 0);
    __syncthreads();
  }

#pragma unroll
  for (int i = 0; i < TM; ++i) {
#pragma unroll
    for (int j = 0; j < TN; ++j) {
      int col = wn + j * 16 + l16;
#pragma unroll
      for (int r = 0; r < 4; ++r) {
        int row = wm + i * 16 + quad * 4 + r;
        float v = acc[i][j][r];
        if (ADD_BIAS) v += bias[n0 + col];
        long idx = (long)(m0 + row) * ldc + (n0 + col);
        if (OUT_BF16) ((unsigned short*)C)[idx] = f2bf(v);
        else ((float*)C)[idx] = v;
      }
    }
  }
}

// ---------------------------------------------------------------------------
extern "C" void kernel_launch(void* const* d_in, const int* in_sizes, int n_in,
                              void* d_out, int out_size, void* d_ws, size_t ws_size,
                              hipStream_t stream) {
  const float* att12 = (const float*)d_in[0];
  const float* att3  = (const float*)d_in[1];
  const float* values = (const float*)d_in[2];
  const float* W_v = (const float*)d_in[3];
  const float* b_v = (const float*)d_in[4];
  const float* W_o = (const float*)d_in[5];
  const float* b_o = (const float*)d_in[6];
  float* out = (float*)d_out;

  char* ws = (char*)d_ws;
  unsigned short* vT    = (unsigned short*)(ws);               // 128 MB [32][512][4096]
  unsigned short* U     = (unsigned short*)(ws + 134217728L);  // 2 MB [2048][512]
  unsigned short* Wvb   = (unsigned short*)(ws + 136314880L);  // 512 KB
  unsigned short* Wob   = (unsigned short*)(ws + 136839168L);  // 512 KB
  float*          bias2 = (float*)(ws + 137363456L);           // 2 KB

  convW<<<dim3(256), dim3(256), 0, stream>>>(W_v, Wvb);
  convW<<<dim3(256), dim3(256), 0, stream>>>(W_o, Wob);
  bias2_kernel<<<dim3(2), dim3(256), 0, stream>>>(W_o, b_v, b_o, bias2);

  vt_gemm<<<dim3(32, 4, 32), dim3(256), 0, stream>>>(Wvb, values, vT);

  o_gemm<<<dim3(256), dim3(256), 0, stream>>>(att12, att3, vT, U);

  // out[(b,q)][e] = U (2048x512) x Wo^T + bias2, fp32
  gemm_bt<64, 64, false, true><<<dim3(8, 32), dim3(256), 0, stream>>>(
      U, Wob, out, bias2, 512, 512, 512, 512);

  (void)in_sizes; (void)n_in; (void)out_size; (void)ws_size;
}

// Round 5
// 551.295 us; speedup vs baseline: 1.1530x; 1.0091x over previous
//
#include <hip/hip_runtime.h>

// B=32 H=8 NQ=64 NK=4096 DIN=512 DV=64 DM=512
typedef short bf16x8 __attribute__((ext_vector_type(8)));
typedef short bf16x4 __attribute__((ext_vector_type(4)));
typedef float f32x4 __attribute__((ext_vector_type(4)));
typedef unsigned int u32x2 __attribute__((ext_vector_type(2)));
typedef unsigned int u32x4 __attribute__((ext_vector_type(4)));

__device__ __forceinline__ unsigned short f2bf(float f) {
  union { float f; unsigned u; } v; v.f = f;
  unsigned r = v.u + 0x7fffu + ((v.u >> 16) & 1u);   // RNE
  return (unsigned short)(r >> 16);
}

// pack two fp32 -> bf16x2 (round-to-nearest, ties up): 2 v_add + 1 v_perm
__device__ __forceinline__ unsigned int pk2(float a, float b) {
  union { float f; unsigned u; } x, y; x.f = a; y.f = b;
  return __builtin_amdgcn_perm(y.u + 0x8000u, x.u + 0x8000u, 0x07060302u);
}

__device__ __forceinline__ void gld_lds16(const void* g, void* l) {
  __builtin_amdgcn_global_load_lds(
      (const __attribute__((address_space(1))) void*)g,
      (__attribute__((address_space(3))) void*)l, 16, 0, 0);
}

// ---------------------------------------------------------------------------
// prep: Wv->bf16 (blocks 0-255), Wo->bf16 (256-511), bias2 (512-513)
// bias2[e] = b_o[e] + sum_d b_v[d]*W_o[e][d]  (exact: softmax rows sum to 1)
__global__ __launch_bounds__(256) void prep(const float* __restrict__ W_v,
                                            const float* __restrict__ W_o,
                                            const float* __restrict__ b_v,
                                            const float* __restrict__ b_o,
                                            unsigned short* __restrict__ Wvb,
                                            unsigned short* __restrict__ Wob,
                                            float* __restrict__ bias2) {
  int bid = blockIdx.x;
  if (bid < 512) {
    const float* in = (bid < 256) ? W_v : W_o;
    unsigned short* out = (bid < 256) ? Wvb : Wob;
    long i = (long)((bid & 255) * 256 + threadIdx.x) * 4;
    f32x4 d = *(const f32x4*)(in + i);
    u32x2 w; w[0] = pk2(d[0], d[1]); w[1] = pk2(d[2], d[3]);
    *(u32x2*)(out + i) = w;
  } else {
    int e = (bid - 512) * 256 + threadIdx.x;
    const float* wrow = W_o + (long)e * 512;
    float s = 0.f;
#pragma unroll 4
    for (int d = 0; d < 512; d += 4) {
      f32x4 w = *(const f32x4*)(wrow + d);
      f32x4 bv = *(const f32x4*)(b_v + d);
      s += w[0] * bv[0] + w[1] * bv[1] + w[2] * bv[2] + w[3] * bv[3];
    }
    bias2[e] = s + b_o[e];
  }
}

// ---------------------------------------------------------------------------
// vT[b][d][nk] = sum_c Wv[d][c] * V[b][nk][c]  (bf16 out)
// Single-barrier K-loop, LDS double-buffered; A async (Wv bf16), B reg-prefetched
// fp32 -> perm-pack -> LDS. BK=32 (64-B rows: conflict-free m97 geometry).
__global__ __launch_bounds__(256, 2) void vt_gemm(
    const unsigned short* __restrict__ Wvb, const float* __restrict__ V,
    unsigned short* __restrict__ vT) {
  const int t = threadIdx.x, lane = t & 63, wave = t >> 6;
  const int n0 = blockIdx.x * 128;   // nk
  const int m0 = blockIdx.y * 128;   // d
  const int b = blockIdx.z;
  const float* Vb = V + (long)b * (4096L * 512) + (long)n0 * 512;

  __shared__ __align__(16) unsigned short As[2][128 * 32];
  __shared__ __align__(16) unsigned short Bs[2][128 * 32];

  const int wm = (wave >> 1) * 64, wn = (wave & 1) * 64;
  const int l16 = lane & 15, quad = lane >> 4;
  const int brow0 = t >> 3, bc4 = (t & 7) * 4;   // B: 8 lanes/row, coalesced

  f32x4 breg[4];
  auto loadB = [&](int k0) {
#pragma unroll
    for (int j = 0; j < 4; ++j)
      breg[j] = *(const f32x4*)(Vb + (long)(brow0 + 32 * j) * 512 + k0 + bc4);
  };
  auto asyncA = [&](int k0, int buf) {
#pragma unroll
    for (int s = 0; s < 2; ++s) {
      int li = s * 256 + t;
      int row = li >> 2, kq = (li & 3) * 8;
      gld_lds16(Wvb + (long)(m0 + row) * 512 + k0 + kq,
                (char*)&As[buf][0] + (s * 256 + wave * 64) * 16);
    }
  };

  f32x4 acc[4][4];
#pragma unroll
  for (int i = 0; i < 4; ++i)
#pragma unroll
    for (int j = 0; j < 4; ++j) acc[i][j] = (f32x4){0.f, 0.f, 0.f, 0.f};

  asyncA(0, 0);
  loadB(0);

  for (int r = 0; r < 16; ++r) {
    const int buf = r & 1;
    // stage B(r): pack prefetched regs -> Bs[buf] (prev readers of Bs[buf]
    // were iter r-2, separated by barrier r-1)
#pragma unroll
    for (int j = 0; j < 4; ++j) {
      u32x2 w;
      w[0] = pk2(breg[j][0], breg[j][1]);
      w[1] = pk2(breg[j][2], breg[j][3]);
      *(u32x2*)(&Bs[buf][(brow0 + 32 * j) * 32 + bc4]) = w;
    }
    __syncthreads();   // drains asyncA(r) + makes Bs[buf] visible
    if (r < 15) {      // prefetch r+1: in flight across the MFMA phase
      loadB((r + 1) * 32);
      asyncA((r + 1) * 32, buf ^ 1);
    }
    bf16x8 af[4], bfv[4];
#pragma unroll
    for (int i = 0; i < 4; ++i)
      af[i] = *(const bf16x8*)(&As[buf][(wm + i * 16 + l16) * 32 + quad * 8]);
#pragma unroll
    for (int j = 0; j < 4; ++j)
      bfv[j] = *(const bf16x8*)(&Bs[buf][(wn + j * 16 + l16) * 32 + quad * 8]);
#pragma unroll
    for (int i = 0; i < 4; ++i)
#pragma unroll
      for (int j = 0; j < 4; ++j)
        acc[i][j] = __builtin_amdgcn_mfma_f32_16x16x32_bf16(af[i], bfv[j], acc[i][j], 0, 0, 0);
  }

  unsigned short* o = vT + (long)b * 2097152;
#pragma unroll
  for (int i = 0; i < 4; ++i)
#pragma unroll
    for (int j = 0; j < 4; ++j) {
      int col = n0 + wn + j * 16 + l16;
#pragma unroll
      for (int r = 0; r < 4; ++r) {
        int row = m0 + wm + i * 16 + quad * 4 + r;
        o[(long)row * 4096 + col] = f2bf(acc[i][j][r]);
      }
    }
}

// ---------------------------------------------------------------------------
// Fused attention per (b,h): U[b][q][h*64+dv] = (1/Z_q) sum_k exp(a12*a3)*vT[d][k]
// Single-barrier dbuf: exps for iter r+1 generated into regs after MFMA issue.
__global__ __launch_bounds__(256, 2) void o_gemm(
    const float* __restrict__ att12, const float* __restrict__ att3,
    const unsigned short* __restrict__ vT, unsigned short* __restrict__ U) {
  const int bh = blockIdx.x;
  const int b = bh >> 3, h = bh & 7;
  const int t = threadIdx.x, lane = t & 63, wave = t >> 6;

  __shared__ __align__(16) unsigned short As[2][4 * 64 * 32];
  __shared__ __align__(16) unsigned short Bs[2][4 * 64 * 32];
  __shared__ float Ored[64 * 68];
  __shared__ float Zl[4][64];
  __shared__ float rZa[64];

  const unsigned short* vTb = vT + (long)b * 2097152 + (long)h * 64 * 4096;
  const int gq = t & 63, gw = t >> 6;          // A-gen: (k-window = wave, q)
  const float* a3row = att3 + ((long)bh * 64 + gq) * 256;
  const float* a12b = att12 + (long)b * 32768 + h * 16;
  const int l16 = lane & 15, quad = lane >> 4;

  f32x4 acc[4][4];
#pragma unroll
  for (int i = 0; i < 4; ++i)
#pragma unroll
    for (int j = 0; j < 4; ++j) acc[i][j] = (f32x4){0.f, 0.f, 0.f, 0.f};
  float zacc = 0.f;

  unsigned int pk[16];
  auto genexp = [&](int r) {
    int kbase = gw * 1024 + r * 32;
    int ch = kbase >> 8, fh = (kbase >> 6) & 3, cw0 = (kbase >> 2) & 15;
    f32x4 y0 = *(const f32x4*)(a3row + ch * 16 + cw0);
    f32x4 y1 = *(const f32x4*)(a3row + ch * 16 + cw0 + 4);
    const float* ap = a12b + ch * 2048 + cw0 * 128 + fh * 4;
#pragma unroll
    for (int cw = 0; cw < 8; ++cw) {
      float y = (cw < 4) ? y0[cw] : y1[cw - 4];
      f32x4 x = *(const f32x4*)(ap + cw * 128);
      float e0 = __expf(x[0] * y), e1 = __expf(x[1] * y);
      float e2 = __expf(x[2] * y), e3 = __expf(x[3] * y);
      zacc += (e0 + e1) + (e2 + e3);
      pk[cw * 2] = pk2(e0, e1);
      pk[cw * 2 + 1] = pk2(e2, e3);
    }
  };
  auto asyncB = [&](int r, int buf) {
#pragma unroll
    for (int s = 0; s < 4; ++s) {
      int row = t >> 2, kq = (t & 3) * 8;
      int kk = s * 1024 + r * 32 + kq;
      gld_lds16(vTb + (long)row * 4096 + kk, (char*)&Bs[buf][0] + s * 4096 + wave * 1024);
    }
  };

  asyncB(0, 0);
  genexp(0);

  for (int r = 0; r < 32; ++r) {
    const int buf = r & 1;
    // write exps(r) regs -> As[buf]
    {
      unsigned short* dst = &As[buf][gw * 2048 + gq * 32];
#pragma unroll
      for (int g = 0; g < 4; ++g)
        *(u32x4*)(dst + g * 8) = (u32x4){pk[g * 4], pk[g * 4 + 1], pk[g * 4 + 2], pk[g * 4 + 3]};
    }
    __syncthreads();   // drains asyncB(r), As[buf] visible
    if (r < 31) asyncB(r + 1, buf ^ 1);
    bf16x8 af[4], bfv[4];
#pragma unroll
    for (int i = 0; i < 4; ++i)
      af[i] = *(const bf16x8*)(&As[buf][wave * 2048 + (i * 16 + l16) * 32 + quad * 8]);
#pragma unroll
    for (int j = 0; j < 4; ++j)
      bfv[j] = *(const bf16x8*)(&Bs[buf][wave * 2048 + (j * 16 + l16) * 32 + quad * 8]);
#pragma unroll
    for (int i = 0; i < 4; ++i)
#pragma unroll
      for (int j = 0; j < 4; ++j)
        acc[i][j] = __builtin_amdgcn_mfma_f32_16x16x32_bf16(af[i], bfv[j], acc[i][j], 0, 0, 0);
    if (r < 31) genexp(r + 1);   // VALU overlaps MFMA execution
  }

  Zl[gw][gq] = zacc;
  __syncthreads();
  if (t < 64) rZa[t] = 1.0f / (Zl[0][t] + Zl[1][t] + Zl[2][t] + Zl[3][t]);
  // sum the 4 wave-accumulators (disjoint k-slices) into Ored
#pragma unroll
  for (int w = 0; w < 4; ++w) {
    if (wave == w) {
#pragma unroll
      for (int i = 0; i < 4; ++i)
#pragma unroll
        for (int j = 0; j < 4; ++j) {
          int col = j * 16 + l16;
#pragma unroll
          for (int rr = 0; rr < 4; ++rr) {
            int row = i * 16 + quad * 4 + rr;
            if (w == 0) Ored[row * 68 + col] = acc[i][j][rr];
            else Ored[row * 68 + col] += acc[i][j][rr];
          }
        }
    }
    __syncthreads();
  }
  // normalize + store bf16: U[(b*64+q)*512 + h*64 + dv]
  {
    int q = t >> 2, dv0 = (t & 3) * 16;
    float rz = rZa[q];
    unsigned short* up = U + ((long)(b * 64 + q)) * 512 + h * 64 + dv0;
    u32x4 o0, o1;
#pragma unroll
    for (int j = 0; j < 4; ++j)
      o0[j] = pk2(Ored[q * 68 + dv0 + 2 * j] * rz, Ored[q * 68 + dv0 + 2 * j + 1] * rz);
#pragma unroll
    for (int j = 0; j < 4; ++j)
      o1[j] = pk2(Ored[q * 68 + dv0 + 8 + 2 * j] * rz, Ored[q * 68 + dv0 + 9 + 2 * j] * rz);
    *(u32x4*)(up) = o0;
    *(u32x4*)(up + 8) = o1;
  }
}

// ---------------------------------------------------------------------------
// Final projection: out[(b,q)][e] = U (2048x512) x Wo^T + bias2  (m97 structure)
template <int BM, int BN>
__global__ __launch_bounds__(256, 2) void gemm_bt(
    const unsigned short* __restrict__ A, const unsigned short* __restrict__ Bt,
    float* __restrict__ C, const float* __restrict__ bias,
    int K, int lda, int ldb, int ldc) {
  constexpr int BK = 32;
  const int t = threadIdx.x;
  const int lane = t & 63;
  const int wave = t >> 6;
  const int m0 = blockIdx.y * BM;
  const int n0 = blockIdx.x * BN;

  A += (long)m0 * lda;
  Bt += (long)n0 * ldb;

  __shared__ __align__(16) unsigned short As[BM * BK];
  __shared__ __align__(16) unsigned short Bs[BN * BK];

  constexpr int TM = BM / 32;
  constexpr int TN = BN / 32;
  const int wm = (wave >> 1) * (BM / 2);
  const int wn = (wave & 1) * (BN / 2);
  const int l16 = lane & 15;
  const int quad = lane >> 4;

  f32x4 acc[TM][TN];
#pragma unroll
  for (int i = 0; i < TM; ++i)
#pragma unroll
    for (int j = 0; j < TN; ++j) acc[i][j] = (f32x4){0.f, 0.f, 0.f, 0.f};

  constexpr int ASHOT = (BM * 4) / 256;
  constexpr int BSHOT = (BN * 4) / 256;

  for (int k0 = 0; k0 < K; k0 += BK) {
#pragma unroll
    for (int s = 0; s < ASHOT; ++s) {
      int li = s * 256 + t;
      int row = li >> 2, kq = (li & 3) * 8;
      gld_lds16(A + (long)row * lda + k0 + kq, (char*)As + (s * 256 + wave * 64) * 16);
    }
#pragma unroll
    for (int s = 0; s < BSHOT; ++s) {
      int li = s * 256 + t;
      int row = li >> 2, kq = (li & 3) * 8;
      gld_lds16(Bt + (long)row * ldb + k0 + kq, (char*)Bs + (s * 256 + wave * 64) * 16);
    }
    __syncthreads();
    bf16x8 af[TM], bfv[TN];
#pragma unroll
    for (int i = 0; i < TM; ++i)
      af[i] = *(const bf16x8*)(As + (wm + i * 16 + l16) * BK + quad * 8);
#pragma unroll
    for (int j = 0; j < TN; ++j)
      bfv[j] = *(const bf16x8*)(Bs + (wn + j * 16 + l16) * BK + quad * 8);
#pragma unroll
    for (int i = 0; i < TM; ++i)
#pragma unroll
      for (int j = 0; j < TN; ++j)
        acc[i][j] = __builtin_amdgcn_mfma_f32_16x16x32_bf16(af[i], bfv[j], acc[i][j], 0, 0, 0);
    __syncthreads();
  }

#pragma unroll
  for (int i = 0; i < TM; ++i) {
#pragma unroll
    for (int j = 0; j < TN; ++j) {
      int col = wn + j * 16 + l16;
#pragma unroll
      for (int r = 0; r < 4; ++r) {
        int row = wm + i * 16 + quad * 4 + r;
        C[(long)(m0 + row) * ldc + (n0 + col)] = acc[i][j][r] + bias[n0 + col];
      }
    }
  }
}

// ---------------------------------------------------------------------------
extern "C" void kernel_launch(void* const* d_in, const int* in_sizes, int n_in,
                              void* d_out, int out_size, void* d_ws, size_t ws_size,
                              hipStream_t stream) {
  const float* att12 = (const float*)d_in[0];
  const float* att3  = (const float*)d_in[1];
  const float* values = (const float*)d_in[2];
  const float* W_v = (const float*)d_in[3];
  const float* b_v = (const float*)d_in[4];
  const float* W_o = (const float*)d_in[5];
  const float* b_o = (const float*)d_in[6];
  float* out = (float*)d_out;

  char* ws = (char*)d_ws;
  unsigned short* vT    = (unsigned short*)(ws);               // 128 MB [32][512][4096]
  unsigned short* U     = (unsigned short*)(ws + 134217728L);  // 2 MB [2048][512]
  unsigned short* Wvb   = (unsigned short*)(ws + 136314880L);  // 512 KB
  unsigned short* Wob   = (unsigned short*)(ws + 136839168L);  // 512 KB
  float*          bias2 = (float*)(ws + 137363456L);           // 2 KB

  prep<<<dim3(514), dim3(256), 0, stream>>>(W_v, W_o, b_v, b_o, Wvb, Wob, bias2);

  vt_gemm<<<dim3(32, 4, 32), dim3(256), 0, stream>>>(Wvb, values, vT);

  o_gemm<<<dim3(256), dim3(256), 0, stream>>>(att12, att3, vT, U);

  gemm_bt<64, 64><<<dim3(8, 32), dim3(256), 0, stream>>>(
      U, Wob, out, bias2, 512, 512, 512, 512);

  (void)in_sizes; (void)n_in; (void)out_size; (void)ws_size;
}